// Round 1
// baseline (141.837 us; speedup 1.0000x reference)
//
#include <hip/hip_runtime.h>
#include <math.h>

// NetVLAD clustering layer, f32, MI355X.
// x:[16,256,1500], centroids:[64,256], lin_w:[66,256], lin_b:[66]
// out: [16, 64*256] f32
//
// Pipeline:
//  K1: soft-assign  a[u,c,t] = softmax_c'(x[u,:,t]·w[c',:]+b)[c<64]   -> ws.a
//  K2: comp partials[chunk][u][c][f] = sum_{t in chunk} a[u,c,t]*x[u,f,t]
//  K3: comp = sum partials - asum*centroid; intra-normalize rows (c)
//  K4: global L2 normalize per utterance

#define NU 16
#define NF 256
#define NT 1500
#define NC 64
#define NCG 66          // clusters + ghosts
#define EPSN 1e-12f

#define T_CHUNK 96      // K2 t-chunk (16B-aligned starts: 96*4B)
#define N_CHUNKS 16     // ceil(1500/96)

// ---------------- helpers ----------------
__device__ __forceinline__ float blk_reduce_sum(float v, float* sbuf) {
    #pragma unroll
    for (int off = 32; off > 0; off >>= 1) v += __shfl_down(v, off, 64);
    const int lane = threadIdx.x & 63, wv = threadIdx.x >> 6;
    if (lane == 0) sbuf[wv] = v;
    __syncthreads();
    float r = sbuf[0] + sbuf[1] + sbuf[2] + sbuf[3];
    __syncthreads();
    return r;
}

// ---------------- K1: assignments ----------------
// grid (24, 16), block 256. Each block: 64 t's; wave w reduces features
// [64w, 64w+64); cross-wave tree reduce in LDS; wave 0 does softmax + store.
__global__ __launch_bounds__(256) void k1_assign(
        const float* __restrict__ x, const float* __restrict__ lin_w,
        const float* __restrict__ lin_b, float* __restrict__ a_ws) {
    const int u    = blockIdx.y;
    const int t0   = blockIdx.x * 64;
    const int tid  = threadIdx.x;
    const int lane = tid & 63;
    const int wave = tid >> 6;
    const int t    = t0 + lane;
    const int tc   = (t < NT) ? t : (NT - 1);   // clamp loads; masked store

    __shared__ float wsm[4][NCG][16];   // per-wave W slice chunk (16 feats)
    __shared__ float red[2][NCG][64];   // cross-wave reduction buffer

    float acc[NCG];
    #pragma unroll
    for (int c = 0; c < NCG; ++c) acc[c] = 0.0f;

    for (int fc = 0; fc < 4; ++fc) {
        const int fbase = wave * 64 + fc * 16;
        // stage W[0:66, fbase:fbase+16] for this wave
        for (int idx = lane; idx < NCG * 16; idx += 64) {
            const int c = idx >> 4, k = idx & 15;
            wsm[wave][c][k] = lin_w[c * NF + fbase + k];
        }
        __syncthreads();

        float xv[16];
        #pragma unroll
        for (int k = 0; k < 16; ++k)
            xv[k] = x[(u * NF + fbase + k) * NT + tc];

        #pragma unroll
        for (int c = 0; c < NCG; ++c) {
            const float4* wr = (const float4*)(&wsm[wave][c][0]);  // 64B-aligned rows
            const float4 w0 = wr[0], w1 = wr[1], w2 = wr[2], w3 = wr[3];
            acc[c] += w0.x*xv[0]  + w0.y*xv[1]  + w0.z*xv[2]  + w0.w*xv[3]
                    + w1.x*xv[4]  + w1.y*xv[5]  + w1.z*xv[6]  + w1.w*xv[7]
                    + w2.x*xv[8]  + w2.y*xv[9]  + w2.z*xv[10] + w2.w*xv[11]
                    + w3.x*xv[12] + w3.y*xv[13] + w3.z*xv[14] + w3.w*xv[15];
        }
        __syncthreads();
    }

    // tree reduce across the 4 waves (each holds a feature-quarter partial)
    if (wave >= 2) {
        #pragma unroll
        for (int c = 0; c < NCG; ++c) red[wave - 2][c][lane] = acc[c];
    }
    __syncthreads();
    if (wave < 2) {
        #pragma unroll
        for (int c = 0; c < NCG; ++c) acc[c] += red[wave][c][lane];
    }
    __syncthreads();
    if (wave == 1) {
        #pragma unroll
        for (int c = 0; c < NCG; ++c) red[0][c][lane] = acc[c];
    }
    __syncthreads();
    if (wave == 0) {
        #pragma unroll
        for (int c = 0; c < NCG; ++c) acc[c] += red[0][c][lane] + lin_b[c];
        // softmax over 66, keep first 64
        float m = -INFINITY;
        #pragma unroll
        for (int c = 0; c < NCG; ++c) m = fmaxf(m, acc[c]);
        float s = 0.0f;
        #pragma unroll
        for (int c = 0; c < NCG; ++c) { acc[c] = __expf(acc[c] - m); s += acc[c]; }
        const float inv = 1.0f / s;
        if (t < NT) {
            #pragma unroll
            for (int c = 0; c < NC; ++c)
                a_ws[(u * NC + c) * NT + t] = acc[c] * inv;   // coalesced per c
        }
    }
}

// ---------------- K2: aggregation GEMM partials ----------------
// grid (N_CHUNKS, 16), block 256. Block computes full 64c x 256f tile for its
// t-chunk. Both operands are t-contiguous in memory. LDS row stride 17 floats
// -> 32 consecutive rows at equal k map to 32 distinct banks (gcd(17,32)=1).
__global__ __launch_bounds__(256) void k2_agg(
        const float* __restrict__ x, const float* __restrict__ a_ws,
        float* __restrict__ partial) {
    const int u = blockIdx.y, chunk = blockIdx.x;
    const int tid = threadIdx.x;
    const int t0 = chunk * T_CHUNK;
    const int t_end = min(t0 + T_CHUNK, NT);

    __shared__ float Asm[64][17];
    __shared__ float Xsm[256][17];

    float acc[8][8];
    #pragma unroll
    for (int i = 0; i < 8; ++i)
        #pragma unroll
        for (int j = 0; j < 8; ++j) acc[i][j] = 0.0f;

    const int cs = tid >> 2;           // staging row 0..63
    const int ks = (tid & 3) * 4;      // staging k offset 0/4/8/12
    const int c_base = (tid >> 5) * 8; // compute: 8 c's
    const int fl = tid & 31;           // compute: f = fl + 32*j

    for (int k0 = t0; k0 < t_end; k0 += 16) {
        const int rem = t_end - k0;
        // stage A (a_ws rows are 16B-aligned: 1500%4==0, k0%16==0... k0-t0%16==0, t0=96*chunk)
        {
            const float* rp = a_ws + (u * NC + cs) * NT + k0 + ks;
            float4 v;
            if (ks + 3 < rem) v = *(const float4*)rp;
            else {
                v.x = (ks + 0 < rem) ? rp[0] : 0.0f;
                v.y = (ks + 1 < rem) ? rp[1] : 0.0f;
                v.z = (ks + 2 < rem) ? rp[2] : 0.0f;
                v.w = (ks + 3 < rem) ? rp[3] : 0.0f;
            }
            Asm[cs][ks+0] = v.x; Asm[cs][ks+1] = v.y;
            Asm[cs][ks+2] = v.z; Asm[cs][ks+3] = v.w;
        }
        // stage X: 4 rows per thread
        #pragma unroll
        for (int r = 0; r < 4; ++r) {
            const int f = cs + 64 * r;
            const float* rp = x + (u * NF + f) * NT + k0 + ks;
            float4 v;
            if (ks + 3 < rem) v = *(const float4*)rp;
            else {
                v.x = (ks + 0 < rem) ? rp[0] : 0.0f;
                v.y = (ks + 1 < rem) ? rp[1] : 0.0f;
                v.z = (ks + 2 < rem) ? rp[2] : 0.0f;
                v.w = (ks + 3 < rem) ? rp[3] : 0.0f;
            }
            Xsm[f][ks+0] = v.x; Xsm[f][ks+1] = v.y;
            Xsm[f][ks+2] = v.z; Xsm[f][ks+3] = v.w;
        }
        __syncthreads();

        #pragma unroll 4
        for (int k = 0; k < 16; ++k) {
            float av[8], xv[8];
            #pragma unroll
            for (int i = 0; i < 8; ++i) av[i] = Asm[c_base + i][k];   // broadcast
            #pragma unroll
            for (int j = 0; j < 8; ++j) xv[j] = Xsm[fl + 32 * j][k];  // conflict-free
            #pragma unroll
            for (int i = 0; i < 8; ++i)
                #pragma unroll
                for (int j = 0; j < 8; ++j) acc[i][j] += av[i] * xv[j];
        }
        __syncthreads();
    }

    // write partials [chunk][u][c][f]
    #pragma unroll
    for (int i = 0; i < 8; ++i) {
        const int c = c_base + i;
        float* op = partial + ((chunk * NU + u) * NC + c) * NF;
        #pragma unroll
        for (int j = 0; j < 8; ++j) op[fl + 32 * j] = acc[i][j];
    }
}

// ---------------- K3: reduce partials, subtract centroid term, intra-norm ----
// grid (64, 16), block 256 (one thread per f).
__global__ __launch_bounds__(256) void k3_norm(
        const float* __restrict__ a_ws, const float* __restrict__ partial,
        const float* __restrict__ centroids, float* __restrict__ compn,
        float* __restrict__ rowsq) {
    const int c = blockIdx.x, u = blockIdx.y;
    const int tid = threadIdx.x;
    __shared__ float sbuf[4];

    // asum[u][c] = sum_t a
    float s = 0.0f;
    const float* arow = a_ws + (u * NC + c) * NT;
    for (int i = tid; i < NT; i += 256) s += arow[i];
    const float asum = blk_reduce_sum(s, sbuf);

    float val = 0.0f;
    #pragma unroll
    for (int ch = 0; ch < N_CHUNKS; ++ch)
        val += partial[((ch * NU + u) * NC + c) * NF + tid];
    val -= asum * centroids[c * NF + tid];

    const float ss = blk_reduce_sum(val * val, sbuf);
    const float d  = fmaxf(sqrtf(ss), EPSN);
    compn[(u * NC + c) * NF + tid] = val / d;
    if (tid == 0) rowsq[u * NC + c] = ss / (d * d);
}

// ---------------- K4: global normalize ----------------
// grid (4, 16), block 256.
__global__ __launch_bounds__(256) void k4_scale(
        const float* __restrict__ compn, const float* __restrict__ rowsq,
        float* __restrict__ out) {
    const int u = blockIdx.y;
    const int tid = threadIdx.x;
    float gss = 0.0f;
    #pragma unroll
    for (int cc = 0; cc < NC; ++cc) gss += rowsq[u * NC + cc];  // uniform -> s_loads
    const float inv = 1.0f / fmaxf(sqrtf(gss), EPSN);
    const int base = u * (NC * NF) + blockIdx.x * 4096;
    #pragma unroll
    for (int r = 0; r < 16; ++r) {
        const int idx = base + r * 256 + tid;
        out[idx] = compn[idx] * inv;
    }
}

// ---------------- launcher ----------------
extern "C" void kernel_launch(void* const* d_in, const int* in_sizes, int n_in,
                              void* d_out, int out_size, void* d_ws, size_t ws_size,
                              hipStream_t stream) {
    (void)in_sizes; (void)n_in; (void)out_size; (void)ws_size;
    const float* x         = (const float*)d_in[0];
    const float* centroids = (const float*)d_in[1];
    const float* lin_w     = (const float*)d_in[2];
    const float* lin_b     = (const float*)d_in[3];
    float* out = (float*)d_out;

    float* ws      = (float*)d_ws;
    float* a_ws    = ws;                                   // 16*64*1500   = 1,536,000 f
    float* partial = a_ws + NU * NC * NT;                  // 16*16*64*256 = 4,194,304 f
    float* compn   = partial + N_CHUNKS * NU * NC * NF;    // 262,144 f
    float* rowsq   = compn + NU * NC * NF;                 // 1,024 f   (total ~24 MB)

    dim3 blk(256);
    hipLaunchKernelGGL(k1_assign, dim3(24, NU), blk, 0, stream, x, lin_w, lin_b, a_ws);
    hipLaunchKernelGGL(k2_agg,    dim3(N_CHUNKS, NU), blk, 0, stream, x, a_ws, partial);
    hipLaunchKernelGGL(k3_norm,   dim3(NC, NU), blk, 0, stream, a_ws, partial, centroids, compn, rowsq);
    hipLaunchKernelGGL(k4_scale,  dim3(4, NU), blk, 0, stream, compn, rowsq, out);
}